// Round 12
// baseline (31.638 us; speedup 1.0000x reference)
//
#include <hip/hip_runtime.h>

#define NG 48
#define NC 16
#define NPTS (NG * NG * NG)
#define E2F 7.3890561f
#define NINE_OVER_E2 1.2180176f     // 9/e^2
#define LOG2E 1.44269504f

#define NSB 6           // 6x6x6 superblocks (8^3 points each); 2x2x2 bricks inside
#define SBSEG 32        // per-(sb,wave) LDS segment cap (lambda ~11, +6.3 sigma)
#define BRCAP 64        // per-brick global list cap (lambda ~28, +6.9 sigma)
#define SEGCAP 48       // fallback fused kernel per-wave segment
#define MAXATOMS 2048

__device__ __forceinline__ float sel_r(int ci) {
    return ci == 0 ? 1.52f : ci == 1 ? 1.7f : ci == 2 ? 1.55f : 1.8f;
}
__device__ __forceinline__ int chan_mask(int ci, int f) {
    int c1 = (f == 14) ? 4 : ((f == 15) ? 6 : f + 4);
    if (f == 12 || f == 13) c1 = -1;
    const int c2 = (f == 14) ? 5 : ((f == 15) ? 9 : -1);
    int mask = 1 << ci;
    if (c1 >= 0) mask |= 1 << c1;
    if (c2 >= 0) mask |= 1 << c2;
    return mask;
}

// ===== Kernel A: two-level build -> exact per-brick candidate lists =====
// 216 blocks x 512 thr. Phase 1: wave w scans atoms [w/8 .. ] (4 lane-parallel
// rounds) into its private LDS sb-segment. Phase 2 (after ONE barrier): wave b
// refines all 8 segments against brick b's box, ballot-compacts (deterministic
// order) into the global brick list.
__global__ __launch_bounds__(512)
void build_kernel(const float* __restrict__ coords,
                  const int* __restrict__ ch_idx,
                  const int* __restrict__ fg,
                  float4* __restrict__ brickAB,   // [(b*BRCAP+o)*2 (+1)]
                  int* __restrict__ counts, int natoms)
{
    __shared__ float4 segA[8 * SBSEG];
    __shared__ float4 segB[8 * SBSEG];
    __shared__ int sCnt[8];

    const int t = threadIdx.x, w = t >> 6, l = t & 63;
    const int sb = blockIdx.x;                       // 0..215
    const int sbx = sb / 36, sby = (sb / 6) % 6, sbz = sb % 6;
    const float lox = sbx * 4.0f, hix = lox + 3.5f;  // superblock point span
    const float loy = sby * 4.0f, hiy = loy + 3.5f;
    const float loz = sbz * 4.0f, hiz = loz + 3.5f;

    // ---- phase 1: wave-private scan (no barriers) ----
    const int eighth = (natoms + 7) >> 3;            // 256 for N=2048
    const int a0 = w * eighth;
    const int a1 = min(a0 + eighth, natoms);
    int cnt = 0;
    #pragma unroll 4
    for (int base = a0; base < a1; base += 64) {
        const int a = base + l;
        bool pred = false;
        float ax = 0.f, ay = 0.f, az = 0.f, r = 1.f, cut = 0.f;
        int ci = 0;
        if (a < a1) {
            ax = coords[3 * a]; ay = coords[3 * a + 1]; az = coords[3 * a + 2];
            ci = ch_idx[a];
            r = sel_r(ci);
            cut = 1.5f * r;
            const float ddx = fmaxf(fmaxf(lox - ax, ax - hix), 0.f);
            const float ddy = fmaxf(fmaxf(loy - ay, ay - hiy), 0.f);
            const float ddz = fmaxf(fmaxf(loz - az, az - hiz), 0.f);
            pred = fmaf(ddx, ddx, fmaf(ddy, ddy, ddz * ddz)) < cut * cut;
        }
        const unsigned long long m = __ballot(pred);
        if (pred) {
            const int o = cnt + __popcll(m & ((1ull << l) - 1ull));
            if (o < SBSEG) {
                const float r2 = r * r;
                const int f = fg[a];                 // survivors only
                segA[w * SBSEG + o] = make_float4(ax, ay, az, cut);
                segB[w * SBSEG + o] = make_float4(-2.0f * LOG2E / r2,
                                                  4.0f / (E2F * r2),
                                                  12.0f / (E2F * r),
                                                  __int_as_float(chan_mask(ci, f)));
            }
        }
        cnt += __popcll(m);
    }
    if (l == 0) sCnt[w] = min(cnt, SBSEG);
    __syncthreads();                                 // the ONLY barrier

    // ---- phase 2: wave b refines to brick b's list (deterministic order) ----
    const int bbx = w >> 2, bby = (w >> 1) & 1, bbz = w & 1;
    const int bx = sbx * 2 + bbx, by = sby * 2 + bby, bz = sbz * 2 + bbz;
    const int b = (bx * 12 + by) * 12 + bz;          // global brick id

    const float blox = bx * 2.0f, bhix = blox + 1.5f;
    const float bloy = by * 2.0f, bhiy = bloy + 1.5f;
    const float bloz = bz * 2.0f, bhiz = bloz + 1.5f;

    int ocnt = 0;
    #pragma unroll 1
    for (int s = 0; s < 8; ++s) {
        const int cs = sCnt[s];
        bool pred = false;
        float4 pA, pB;
        if (l < cs) {
            pA = segA[s * SBSEG + l];
            pB = segB[s * SBSEG + l];
            const float ddx = fmaxf(fmaxf(blox - pA.x, pA.x - bhix), 0.f);
            const float ddy = fmaxf(fmaxf(bloy - pA.y, pA.y - bhiy), 0.f);
            const float ddz = fmaxf(fmaxf(bloz - pA.z, pA.z - bhiz), 0.f);
            pred = fmaf(ddx, ddx, fmaf(ddy, ddy, ddz * ddz)) < pA.w * pA.w;
        }
        const unsigned long long m = __ballot(pred);
        if (pred) {
            const int o = ocnt + __popcll(m & ((1ull << l) - 1ull));
            if (o < BRCAP) {
                brickAB[((size_t)b * BRCAP + o) * 2 + 0] = pA;
                brickAB[((size_t)b * BRCAP + o) * 2 + 1] = pB;
            }
        }
        ocnt += __popcll(m);
    }
    if (l == 0) counts[b] = min(ocnt, BRCAP);
}

// ===== Kernel B: density. Stage brick list (no tests) -> gather -> store. =====
// 1728 blocks x 4 waves; wave w accumulates only channels 4w..4w+3 (acc[4]),
// so there is NO cross-wave reduction. One barrier total.
__global__ __launch_bounds__(256)
void density_kernel(const float4* __restrict__ brickAB,
                    const int* __restrict__ counts,
                    float* __restrict__ out)
{
    __shared__ float4 sA[BRCAP];
    __shared__ float4 sB[BRCAP];

    const int t = threadIdx.x, w = t >> 6, l = t & 63;
    const int bz = blockIdx.x, by = blockIdx.y, bx = blockIdx.z;
    const int b = (bx * 12 + by) * 12 + bz;

    const int cnt = counts[b];                       // block-uniform
    if (t < cnt) {                                   // lane-parallel stage, no ballot
        sA[t] = brickAB[((size_t)b * BRCAP + t) * 2 + 0];
        sB[t] = brickAB[((size_t)b * BRCAP + t) * 2 + 1];
    }
    __syncthreads();                                 // the ONLY barrier

    // lane -> grid point (same 64 points for every wave)
    const int tz = l & 3, ty = (l >> 2) & 3, tx = l >> 4;
    const float px = (bx * 4 + tx) * 0.5f;
    const float py = (by * 4 + ty) * 0.5f;
    const float pz = (bz * 4 + tz) * 0.5f;

    float acc[4] = {0.f, 0.f, 0.f, 0.f};

    float4 A0, B0;
    if (cnt > 0) { A0 = sA[0]; B0 = sB[0]; }
    for (int i = 0; i < cnt; ++i) {
        float4 A1 = A0, B1 = B0;
        if (i + 1 < cnt) { A1 = sA[i + 1]; B1 = sB[i + 1]; }
        const float dx = px - A0.x;
        const float dy = py - A0.y;
        const float dz = pz - A0.z;
        const float d2 = fmaf(dx, dx, fmaf(dy, dy, dz * dz));
        const float cut2 = A0.w * A0.w;
        const float r2 = cut2 * (4.0f / 9.0f);
        const float d  = sqrtf(d2);
        const float f1 = exp2f(B0.x * d2);                    // exp(-2 d2/r2)
        const float f2 = fmaf(B0.y, d2, fmaf(-B0.z, d, NINE_OVER_E2));
        float val = (d2 < r2) ? f1 : f2;
        val = (d2 < cut2) ? val : 0.0f;
        const int chan = __builtin_amdgcn_readfirstlane(__float_as_int(B0.w)) >> (w * 4);
        #pragma unroll
        for (int k = 0; k < 4; ++k) {
            const float msk = __int_as_float(((chan >> k) & 1) * 0x3f800000);
            acc[k] = fmaf(msk, val, acc[k]);         // branch-free, 4 fma/candidate
        }
        A0 = A1; B0 = B1;
    }

    const int pbase = ((bx * 4 + tx) * NG + by * 4 + ty) * NG + bz * 4 + tz;
    #pragma unroll
    for (int k = 0; k < 4; ++k)
        out[(w * 4 + k) * NPTS + pbase] = acc[k];
}

// ===== Fallback: R9 fused single kernel (small ws / large natoms) =====
__global__ __launch_bounds__(256)
void density_fused_kernel(const float* __restrict__ coords,
                          const int* __restrict__ ch_idx,
                          const int* __restrict__ fg,
                          float* __restrict__ out, int natoms)
{
    __shared__ float4 sA[4 * SEGCAP];
    __shared__ float4 sB[4 * SEGCAP];
    __shared__ float sRed[4 * NC][64];

    const int t = threadIdx.x, w = t >> 6, l = t & 63;
    const int bz = blockIdx.x, by = blockIdx.y, bx = blockIdx.z;

    const float lox = bx * 2.0f, hix = lox + 1.5f;
    const float loy = by * 2.0f, hiy = loy + 1.5f;
    const float loz = bz * 2.0f, hiz = loz + 1.5f;

    const int quarter = (natoms + 3) >> 2;
    const int a0 = w * quarter;
    const int a1 = min(a0 + quarter, natoms);
    int cnt = 0;
    #pragma unroll 4
    for (int base = a0; base < a1; base += 64) {
        const int a = base + l;
        bool pred = false;
        float ax = 0.f, ay = 0.f, az = 0.f, r = 1.f, cut = 0.f;
        int ci = 0;
        if (a < a1) {
            ax = coords[3 * a]; ay = coords[3 * a + 1]; az = coords[3 * a + 2];
            ci = ch_idx[a];
            r = sel_r(ci);
            cut = 1.5f * r;
            const float ddx = fmaxf(fmaxf(lox - ax, ax - hix), 0.f);
            const float ddy = fmaxf(fmaxf(loy - ay, ay - hiy), 0.f);
            const float ddz = fmaxf(fmaxf(loz - az, az - hiz), 0.f);
            pred = fmaf(ddx, ddx, fmaf(ddy, ddy, ddz * ddz)) < cut * cut;
        }
        const unsigned long long m = __ballot(pred);
        if (pred) {
            const int o = cnt + __popcll(m & ((1ull << l) - 1ull));
            if (o < SEGCAP) {
                const float r2 = r * r;
                const int f = fg[a];
                sA[w * SEGCAP + o] = make_float4(ax, ay, az, cut);
                sB[w * SEGCAP + o] = make_float4(-2.0f * LOG2E / r2,
                                                 4.0f / (E2F * r2),
                                                 12.0f / (E2F * r),
                                                 __int_as_float(chan_mask(ci, f)));
            }
        }
        cnt += __popcll(m);
    }
    cnt = min(cnt, SEGCAP);

    const int tz = l & 3, ty = (l >> 2) & 3, tx = l >> 4;
    const float px = (bx * 4 + tx) * 0.5f;
    const float py = (by * 4 + ty) * 0.5f;
    const float pz = (bz * 4 + tz) * 0.5f;

    float acc[NC];
    #pragma unroll
    for (int c = 0; c < NC; ++c) acc[c] = 0.0f;

    const int segbase = w * SEGCAP;
    float4 A0, B0;
    if (cnt > 0) { A0 = sA[segbase]; B0 = sB[segbase]; }
    for (int i = 0; i < cnt; ++i) {
        float4 A1 = A0, B1 = B0;
        if (i + 1 < cnt) { A1 = sA[segbase + i + 1]; B1 = sB[segbase + i + 1]; }
        const float dx = px - A0.x;
        const float dy = py - A0.y;
        const float dz = pz - A0.z;
        const float d2 = fmaf(dx, dx, fmaf(dy, dy, dz * dz));
        const float cut2 = A0.w * A0.w;
        const float r2 = cut2 * (4.0f / 9.0f);
        const float d  = sqrtf(d2);
        const float f1 = exp2f(B0.x * d2);
        const float f2 = fmaf(B0.y, d2, fmaf(-B0.z, d, NINE_OVER_E2));
        float val = (d2 < r2) ? f1 : f2;
        val = (d2 < cut2) ? val : 0.0f;
        const int chan = __builtin_amdgcn_readfirstlane(__float_as_int(B0.w));
        #pragma unroll
        for (int c = 0; c < NC; ++c) {
            const float msk = __int_as_float(((chan >> c) & 1) * 0x3f800000);
            acc[c] = fmaf(msk, val, acc[c]);
        }
        A0 = A1; B0 = B1;
    }

    #pragma unroll
    for (int c = 0; c < NC; ++c) sRed[w * NC + c][l] = acc[c];
    __syncthreads();

    const int chl = l >> 4;
    const int xy  = l & 15;
    const int c   = w * 4 + chl;
    float4 s = *(const float4*)&sRed[0 * NC + c][xy * 4];
    const float4 s1 = *(const float4*)&sRed[1 * NC + c][xy * 4];
    const float4 s2 = *(const float4*)&sRed[2 * NC + c][xy * 4];
    const float4 s3 = *(const float4*)&sRed[3 * NC + c][xy * 4];
    s.x += s1.x + s2.x + s3.x;
    s.y += s1.y + s2.y + s3.y;
    s.z += s1.z + s2.z + s3.z;
    s.w += s1.w + s2.w + s3.w;

    const int gx = bx * 4 + (xy >> 2);
    const int gy = by * 4 + (xy & 3);
    const int gz0 = bz * 4;
    *(float4*)&out[c * NPTS + (gx * NG + gy) * NG + gz0] = s;
}

extern "C" void kernel_launch(void* const* d_in, const int* in_sizes, int n_in,
                              void* d_out, int out_size, void* d_ws, size_t ws_size,
                              hipStream_t stream) {
    (void)n_in; (void)out_size;
    const float* coords = (const float*)d_in[0];
    const int* ch = (const int*)d_in[1];
    const int* fgp = (const int*)d_in[2];
    float* out = (float*)d_out;
    const int natoms = in_sizes[0] / 3;

    const int nbricks = 12 * 12 * 12;                          // 1728
    const size_t cnt_bytes = ((size_t)nbricks * sizeof(int) + 255) & ~255ull;
    const size_t need = cnt_bytes + (size_t)nbricks * BRCAP * 2 * sizeof(float4);
    dim3 grid(12, 12, 12);                                     // (bz, by, bx)

    if (natoms <= MAXATOMS && ws_size >= need) {
        int* counts = (int*)d_ws;
        float4* brickAB = (float4*)((char*)d_ws + cnt_bytes);
        build_kernel<<<216, 512, 0, stream>>>(coords, ch, fgp, brickAB, counts, natoms);
        density_kernel<<<grid, 256, 0, stream>>>(brickAB, counts, out);
    } else {
        density_fused_kernel<<<grid, 256, 0, stream>>>(coords, ch, fgp, out, natoms);
    }
}

// Round 13
// 21.286 us; speedup vs baseline: 1.4864x; 1.4864x over previous
//
#include <hip/hip_runtime.h>

#define NG 48
#define NC 16
#define NPTS (NG * NG * NG)
#define E2F 7.3890561f
#define NINE_OVER_E2 1.2180175f
#define LOG2E 1.44269504f

#define BR 4            // 4x4x4 grid-point brick per block
#define SEGCAP 48       // per-wave LDS candidate segment (expected ~6.4, +17 sigma)
#define SBCAP 512       // per-superblock candidate cap (expected ~320, +12 sigma)
#define MAXATOMS 2048

__device__ __constant__ float c_vdw[4] = {1.52f, 1.7f, 1.55f, 1.8f};

__device__ __forceinline__ void atom_params(int ci, int f, float r,
                                            float& b0, float& b1, float& b2, int& mask) {
    const float r2 = r * r;
    int c1 = (f == 14) ? 4 : ((f == 15) ? 6 : f + 4);
    if (f == 12 || f == 13) c1 = -1;
    const int c2 = (f == 14) ? 5 : ((f == 15) ? 9 : -1);
    mask = 1 << ci;
    if (c1 >= 0) mask |= 1 << c1;
    if (c2 >= 0) mask |= 1 << c2;
    b0 = -2.0f * LOG2E / r2;     // exp2-folded gaussian coef
    b1 = 4.0f / (E2F * r2);
    b2 = 12.0f / (E2F * r);
}

// ================= Kernel A: fused prep + per-superblock candidate build ==========
__global__ __launch_bounds__(1024)
void build_kernel(const float* __restrict__ coords,
                  const int* __restrict__ ch_idx,
                  const int* __restrict__ fg,
                  float4* __restrict__ segA, float4* __restrict__ segB,
                  int* __restrict__ counts, int natoms)
{
    __shared__ float sx[MAXATOMS], sy[MAXATOMS], sz[MAXATOMS], scut[MAXATOMS];
    __shared__ float sb0[MAXATOMS], sb1[MAXATOMS], sb2[MAXATOMS], sb3[MAXATOMS];
    __shared__ int sCnt[16];

    const int t = threadIdx.x, w = t >> 6, l = t & 63;
    const int n = min(natoms, MAXATOMS);

    for (int i = t; i < n; i += 1024) {
        const float x = coords[3 * i], y = coords[3 * i + 1], z = coords[3 * i + 2];
        const int ci = ch_idx[i], f = fg[i];
        const float r = c_vdw[ci];
        float b0, b1, b2; int mask;
        atom_params(ci, f, r, b0, b1, b2, mask);
        sx[i] = x; sy[i] = y; sz[i] = z; scut[i] = 1.5f * r;
        sb0[i] = b0; sb1[i] = b1; sb2[i] = b2; sb3[i] = __int_as_float(mask);
    }
    __syncthreads();

    const int sb = blockIdx.x;                       // 0..26
    const int sbx = sb / 9, sby = (sb / 3) % 3, sbz = sb % 3;
    const float lox = sbx * 8.0f, hix = lox + 7.5f;  // 16-point span
    const float loy = sby * 8.0f, hiy = loy + 7.5f;
    const float loz = sbz * 8.0f, hiz = loz + 7.5f;

    int runTot = 0;
    for (int base = 0; base < n; base += 1024) {
        const int a = base + t;
        bool pred = false;
        float ax = 0.f, ay = 0.f, az = 0.f, cut = 0.f;
        if (a < n) {
            ax = sx[a]; ay = sy[a]; az = sz[a]; cut = scut[a];
            const float ddx = fmaxf(fmaxf(lox - ax, ax - hix), 0.f);
            const float ddy = fmaxf(fmaxf(loy - ay, ay - hiy), 0.f);
            const float ddz = fmaxf(fmaxf(loz - az, az - hiz), 0.f);
            pred = fmaf(ddx, ddx, fmaf(ddy, ddy, ddz * ddz)) < cut * cut;
        }
        const unsigned long long m = __ballot(pred);
        if (l == 0) sCnt[w] = __popcll(m);
        __syncthreads();
        int ofs = runTot, tot = 0;
        #pragma unroll
        for (int w2 = 0; w2 < 16; ++w2) {
            const int c = sCnt[w2];
            if (w2 < w) ofs += c;
            tot += c;
        }
        if (pred) {
            const int o = ofs + __popcll(m & ((1ull << l) - 1ull));
            if (o < SBCAP) {
                segA[sb * SBCAP + o] = make_float4(ax, ay, az, cut);
                segB[sb * SBCAP + o] = make_float4(sb0[a], sb1[a], sb2[a], sb3[a]);
            }
        }
        runTot += tot;
        __syncthreads();
    }
    if (t == 0) counts[sb] = min(runTot, SBCAP);
}

// ================= Kernel B: refine superblock list + gather =====================
__global__ __launch_bounds__(256)
void density_kernel(const float4* __restrict__ segA,
                    const float4* __restrict__ segB,
                    const int* __restrict__ counts,
                    float* __restrict__ out)
{
    __shared__ __align__(16) unsigned char smem[16384];   // sA/sB, later sRed
    __shared__ int sCnt[4];
    float4* const sA = (float4*)smem;                     // [4*SEGCAP]
    float4* const sB = sA + 4 * SEGCAP;
    float (*const sRed)[64] = (float (*)[64])smem;        // [4*NC][64]

    const int t = threadIdx.x, w = t >> 6, l = t & 63;
    const int bz = blockIdx.x, by = blockIdx.y, bx = blockIdx.z;

    const float blox = bx * 2.0f, bhix = blox + 1.5f;
    const float bloy = by * 2.0f, bhiy = bloy + 1.5f;
    const float bloz = bz * 2.0f, bhiz = bloz + 1.5f;

    const int sb = ((bx >> 2) * 3 + (by >> 2)) * 3 + (bz >> 2);
    const int cnt_sb = counts[sb];
    const float4* const srcA = segA + sb * SBCAP;
    const float4* const srcB = segB + sb * SBCAP;

    // ---- wave-private refine of a contiguous quarter of the superblock list ----
    const int q = (cnt_sb + 3) >> 2;
    const int i0 = w * q, i1 = min(i0 + q, cnt_sb);
    int myCnt = 0;
    for (int base = i0; base < i1; base += 64) {
        const int idx = base + l;
        bool pred = false;
        float4 pA, pB;
        if (idx < i1) {
            pA = srcA[idx];
            pB = srcB[idx];
            const float ddx = fmaxf(fmaxf(blox - pA.x, pA.x - bhix), 0.f);
            const float ddy = fmaxf(fmaxf(bloy - pA.y, pA.y - bhiy), 0.f);
            const float ddz = fmaxf(fmaxf(bloz - pA.z, pA.z - bhiz), 0.f);
            pred = fmaf(ddx, ddx, fmaf(ddy, ddy, ddz * ddz)) < pA.w * pA.w;
        }
        const unsigned long long m = __ballot(pred);
        if (pred) {
            const int o = myCnt + __popcll(m & ((1ull << l) - 1ull));
            if (o < SEGCAP) { sA[w * SEGCAP + o] = pA; sB[w * SEGCAP + o] = pB; }
        }
        myCnt += __popcll(m);
    }
    if (l == 0) sCnt[w] = min(myCnt, SEGCAP);
    __syncthreads();

    const int c0 = sCnt[0], c1 = sCnt[1], c2 = sCnt[2], c3 = sCnt[3];

    // lane -> grid point (4x4x4 brick)
    const int tz = l & 3, ty = (l >> 2) & 3, tx = l >> 4;
    const float px = (bx * BR + tx) * 0.5f;
    const float py = (by * BR + ty) * 0.5f;
    const float pz = (bz * BR + tz) * 0.5f;

    float acc[NC];
    #pragma unroll
    for (int c = 0; c < NC; ++c) acc[c] = 0.0f;

    #pragma unroll 1
    for (int s = 0; s < 4; ++s) {
        const int cs = (s == 0) ? c0 : (s == 1) ? c1 : (s == 2) ? c2 : c3;
        const int segbase = s * SEGCAP;
        #pragma unroll 2
        for (int i = w; i < cs; i += 4) {
            const float4 A = sA[segbase + i];     // wave-uniform broadcast
            const float4 B = sB[segbase + i];
            const float dx = px - A.x;
            const float dy = py - A.y;
            const float dz = pz - A.z;
            const float d2 = fmaf(dx, dx, fmaf(dy, dy, dz * dz));
            const float cut2 = A.w * A.w;
            if (d2 < cut2) {
                const float r2 = cut2 * (4.0f / 9.0f);
                const float d  = sqrtf(d2);
                const float f1 = exp2f(B.x * d2);
                const float f2 = fmaf(B.y, d2, fmaf(-B.z, d, NINE_OVER_E2));
                const float val = (d2 < r2) ? f1 : f2;
                const int chan = __builtin_amdgcn_readfirstlane(__float_as_int(B.w));
                #pragma unroll
                for (int c = 0; c < NC; ++c)
                    if (chan & (1 << c)) acc[c] += val;   // scalar-branched
            }
        }
    }
    __syncthreads();   // gather done -> safe to overwrite sA/sB with sRed

    #pragma unroll
    for (int c = 0; c < NC; ++c) sRed[w * NC + c][l] = acc[c];
    __syncthreads();

    const int gx = bx * BR + tx, gy = by * BR + ty, gz = bz * BR + tz;
    const int pbase = (gx * NG + gy) * NG + gz;
    #pragma unroll
    for (int k = 0; k < 4; ++k) {
        const int c = w * 4 + k;
        const float s = sRed[0 * NC + c][l] + sRed[1 * NC + c][l] +
                        sRed[2 * NC + c][l] + sRed[3 * NC + c][l];
        out[c * NPTS + pbase] = s;
    }
}

// ================= Fallback (R3 path) for small ws / large natoms ================
__global__ void prep_kernel(const float* __restrict__ coords,
                            const int* __restrict__ ch_idx,
                            const int* __restrict__ fg,
                            float4* __restrict__ atomA,
                            float4* __restrict__ atomB, int natoms)
{
    const int i = blockIdx.x * blockDim.x + threadIdx.x;
    if (i >= natoms) return;
    const int ci = ch_idx[i], f = fg[i];
    const float r = c_vdw[ci];
    float b0, b1, b2; int mask;
    atom_params(ci, f, r, b0, b1, b2, mask);
    atomA[i] = make_float4(coords[3 * i], coords[3 * i + 1], coords[3 * i + 2], 1.5f * r);
    atomB[i] = make_float4(b0, b1, b2, __int_as_float(mask));
}

__global__ __launch_bounds__(256)
void density_scan_kernel(const float4* __restrict__ atomA,
                         const float4* __restrict__ atomB,
                         float* __restrict__ out, int natoms)
{
    __shared__ __align__(16) unsigned char smem[16384];
    __shared__ int sCnt[4];
    float4* const sA = (float4*)smem;
    float4* const sB = sA + 4 * SEGCAP;
    float (*const sRed)[64] = (float (*)[64])smem;

    const int t = threadIdx.x, w = t >> 6, l = t & 63;
    const int bz = blockIdx.x, by = blockIdx.y, bx = blockIdx.z;

    const float blox = bx * 2.0f, bhix = blox + 1.5f;
    const float bloy = by * 2.0f, bhiy = bloy + 1.5f;
    const float bloz = bz * 2.0f, bhiz = bloz + 1.5f;

    const int quarter = (natoms + 3) >> 2;
    const int a0 = w * quarter, a1 = min(a0 + quarter, natoms);
    int myCnt = 0;
    for (int base = a0; base < a1; base += 64) {
        const int a = base + l;
        bool pred = false; float4 pA;
        if (a < a1) {
            pA = atomA[a];
            const float ddx = fmaxf(fmaxf(blox - pA.x, pA.x - bhix), 0.f);
            const float ddy = fmaxf(fmaxf(bloy - pA.y, pA.y - bhiy), 0.f);
            const float ddz = fmaxf(fmaxf(bloz - pA.z, pA.z - bhiz), 0.f);
            pred = fmaf(ddx, ddx, fmaf(ddy, ddy, ddz * ddz)) < pA.w * pA.w;
        }
        const unsigned long long m = __ballot(pred);
        if (pred) {
            const int o = myCnt + __popcll(m & ((1ull << l) - 1ull));
            if (o < SEGCAP) { sA[w * SEGCAP + o] = pA; sB[w * SEGCAP + o] = atomB[a]; }
        }
        myCnt += __popcll(m);
    }
    if (l == 0) sCnt[w] = min(myCnt, SEGCAP);
    __syncthreads();

    const int c0 = sCnt[0], c1 = sCnt[1], c2 = sCnt[2], c3 = sCnt[3];
    const int tz = l & 3, ty = (l >> 2) & 3, tx = l >> 4;
    const float px = (bx * BR + tx) * 0.5f;
    const float py = (by * BR + ty) * 0.5f;
    const float pz = (bz * BR + tz) * 0.5f;

    float acc[NC];
    #pragma unroll
    for (int c = 0; c < NC; ++c) acc[c] = 0.0f;

    #pragma unroll 1
    for (int s = 0; s < 4; ++s) {
        const int cs = (s == 0) ? c0 : (s == 1) ? c1 : (s == 2) ? c2 : c3;
        const int segbase = s * SEGCAP;
        #pragma unroll 2
        for (int i = w; i < cs; i += 4) {
            const float4 A = sA[segbase + i];
            const float4 B = sB[segbase + i];
            const float dx = px - A.x, dy = py - A.y, dz = pz - A.z;
            const float d2 = fmaf(dx, dx, fmaf(dy, dy, dz * dz));
            const float cut2 = A.w * A.w;
            if (d2 < cut2) {
                const float r2 = cut2 * (4.0f / 9.0f);
                const float d  = sqrtf(d2);
                const float f1 = exp2f(B.x * d2);
                const float f2 = fmaf(B.y, d2, fmaf(-B.z, d, NINE_OVER_E2));
                const float val = (d2 < r2) ? f1 : f2;
                const int chan = __builtin_amdgcn_readfirstlane(__float_as_int(B.w));
                #pragma unroll
                for (int c = 0; c < NC; ++c)
                    if (chan & (1 << c)) acc[c] += val;
            }
        }
    }
    __syncthreads();
    #pragma unroll
    for (int c = 0; c < NC; ++c) sRed[w * NC + c][l] = acc[c];
    __syncthreads();

    const int gx = bx * BR + tx, gy = by * BR + ty, gz = bz * BR + tz;
    const int pbase = (gx * NG + gy) * NG + gz;
    #pragma unroll
    for (int k = 0; k < 4; ++k) {
        const int c = w * 4 + k;
        out[c * NPTS + pbase] = sRed[0 * NC + c][l] + sRed[1 * NC + c][l] +
                                sRed[2 * NC + c][l] + sRed[3 * NC + c][l];
    }
}

extern "C" void kernel_launch(void* const* d_in, const int* in_sizes, int n_in,
                              void* d_out, int out_size, void* d_ws, size_t ws_size,
                              hipStream_t stream) {
    (void)n_in; (void)out_size;
    const float* coords = (const float*)d_in[0];
    const int* ch = (const int*)d_in[1];
    const int* fgp = (const int*)d_in[2];
    float* out = (float*)d_out;
    const int natoms = in_sizes[0] / 3;

    const size_t need = 256 + 2ull * 27 * SBCAP * sizeof(float4);
    dim3 grid(NG / BR, NG / BR, NG / BR);   // (bz, by, bx) = 12^3

    if (natoms <= MAXATOMS && ws_size >= need) {
        int* counts = (int*)d_ws;
        float4* segA = (float4*)((char*)d_ws + 256);
        float4* segB = segA + 27 * SBCAP;
        build_kernel<<<27, 1024, 0, stream>>>(coords, ch, fgp, segA, segB, counts, natoms);
        density_kernel<<<grid, 256, 0, stream>>>(segA, segB, counts, out);
    } else {
        float4* atomA = (float4*)d_ws;
        float4* atomB = atomA + natoms;
        prep_kernel<<<(natoms + 255) / 256, 256, 0, stream>>>(coords, ch, fgp, atomA, atomB, natoms);
        density_scan_kernel<<<grid, 256, 0, stream>>>(atomA, atomB, out, natoms);
    }
}